// Round 1
// baseline (3134.046 us; speedup 1.0000x reference)
//
#include <hip/hip_runtime.h>
#include <math.h>

#define HW 116
#define CIN 4

// ---------------- weight transpose prep: w[c][k] -> wt[k][c] ----------------
__global__ __launch_bounds__(256) void k_prep(const float* __restrict__ c1w,
                                              const float* __restrict__ c2w,
                                              const float* __restrict__ c3w,
                                              float* __restrict__ wt1,
                                              float* __restrict__ wt2,
                                              float* __restrict__ wt3) {
    int i = blockIdx.x * 256 + threadIdx.x;
    if (i < 8192)  { int c = i >> 8, k = i & 255; wt1[k * 32 + c] = c1w[i]; }
    if (i < 32768) { int c = i >> 9, k = i & 511; wt2[k * 64 + c] = c2w[i]; }
    if (i < 36864) { int c = i / 576, k = i % 576; wt3[k * 64 + c] = c3w[i]; }
}

// ---------------- conv1: (n,4,116,116) -> (n,32,28,28), stride4 k8, ReLU ----
__global__ __launch_bounds__(256) void k_conv1(const float* __restrict__ x,
                                               const float* __restrict__ wt,
                                               const float* __restrict__ bias,
                                               float* __restrict__ out,
                                               int n0, int nImg) {
    const int SL = 28 * 14;  // P=2 pixels along ox
    int idx = blockIdx.x * 256 + threadIdx.x;
    int li = idx / SL;
    if (li >= nImg) return;
    int s = idx % SL;
    int oy = s / 14, og = s % 14, ox0 = og * 2;
    int n = n0 + li;
    const float* xb = x + (size_t)n * (CIN * HW * HW) + (size_t)(oy * 4) * HW + ox0 * 4;
    float acc0[32], acc1[32];
#pragma unroll
    for (int c = 0; c < 32; c++) { acc0[c] = 0.f; acc1[c] = 0.f; }
    for (int ci = 0; ci < 4; ci++)
        for (int kh = 0; kh < 8; kh++) {
            const float* xr = xb + ci * (HW * HW) + kh * HW;
            const float* wr = wt + ((ci * 8 + kh) * 8) * 32;
#pragma unroll
            for (int kw = 0; kw < 8; kw++) {
                float v0 = xr[kw], v1 = xr[kw + 4];
                const float* wk = wr + kw * 32;
#pragma unroll
                for (int c = 0; c < 32; c++) {
                    float wv = wk[c];
                    acc0[c] += v0 * wv;
                    acc1[c] += v1 * wv;
                }
            }
        }
    float* ob = out + (size_t)li * (32 * 28 * 28) + oy * 28 + ox0;
#pragma unroll
    for (int c = 0; c < 32; c++) {
        float bb = bias[c];
        ob[c * 784] = fmaxf(acc0[c] + bb, 0.f);
        ob[c * 784 + 1] = fmaxf(acc1[c] + bb, 0.f);
    }
}

// ---------------- conv2: (li,32,28,28) -> (n,64,13,13), stride2 k4, ReLU ----
__global__ __launch_bounds__(256) void k_conv2(const float* __restrict__ hin,
                                               const float* __restrict__ wt,
                                               const float* __restrict__ bias,
                                               float* __restrict__ out,
                                               int n0, int nImg) {
    const int SL = 13 * 7;
    int idx = blockIdx.x * 256 + threadIdx.x;
    int li = idx / SL;
    if (li >= nImg) return;
    int s = idx % SL;
    int oy = s / 7, og = s % 7, ox0 = og * 2;
    const float* xb = hin + (size_t)li * (32 * 28 * 28) + (size_t)(oy * 2) * 28 + ox0 * 2;
    float acc0[64], acc1[64];
#pragma unroll
    for (int c = 0; c < 64; c++) { acc0[c] = 0.f; acc1[c] = 0.f; }
    for (int ci = 0; ci < 32; ci++)
        for (int kh = 0; kh < 4; kh++) {
            const float* xr = xb + ci * 784 + kh * 28;
            const float* wr = wt + ((ci * 4 + kh) * 4) * 64;
#pragma unroll
            for (int kw = 0; kw < 4; kw++) {
                float v0 = xr[kw], v1 = xr[kw + 2];  // v1 may read 1 elem OOB of chunk; discarded when !p1
                const float* wk = wr + kw * 64;
#pragma unroll
                for (int c = 0; c < 64; c++) {
                    float wv = wk[c];
                    acc0[c] += v0 * wv;
                    acc1[c] += v1 * wv;
                }
            }
        }
    bool p1 = (ox0 + 1) < 13;
    float* ob = out + (size_t)(n0 + li) * (64 * 169) + oy * 13 + ox0;
#pragma unroll
    for (int c = 0; c < 64; c++) {
        float bb = bias[c];
        ob[c * 169] = fmaxf(acc0[c] + bb, 0.f);
        if (p1) ob[c * 169 + 1] = fmaxf(acc1[c] + bb, 0.f);
    }
}

// ---------------- conv3: (n,64,13,13) -> (n,64,6,6) CHW-flat, stride2 k3 ----
__global__ __launch_bounds__(256) void k_conv3(const float* __restrict__ hin,
                                               const float* __restrict__ wt,
                                               const float* __restrict__ bias,
                                               float* __restrict__ out) {
    const int SL = 36;
    int idx = blockIdx.x * 256 + threadIdx.x;
    int n = idx / SL;
    if (n >= 2048) return;
    int s = idx % SL;
    int oy = s / 6, ox = s % 6;
    const float* xb = hin + (size_t)n * (64 * 169) + (size_t)(oy * 2) * 13 + ox * 2;
    float acc[64];
#pragma unroll
    for (int c = 0; c < 64; c++) acc[c] = 0.f;
    for (int ci = 0; ci < 64; ci++)
        for (int kh = 0; kh < 3; kh++) {
            const float* xr = xb + ci * 169 + kh * 13;
            const float* wr = wt + ((ci * 3 + kh) * 3) * 64;
#pragma unroll
            for (int kw = 0; kw < 3; kw++) {
                float v = xr[kw];
                const float* wk = wr + kw * 64;
#pragma unroll
                for (int c = 0; c < 64; c++) acc[c] += v * wk[c];
            }
        }
    float* ob = out + (size_t)n * 2304 + s;
#pragma unroll
    for (int c = 0; c < 64; c++) ob[c * 36] = fmaxf(acc[c] + bias[c], 0.f);
}

// ---------------- CBAM + spatial self-attention (per-image block) ----------
__global__ __launch_bounds__(256) void k_cbam_attn(float* __restrict__ h,  // (N,64,36) in-place
                                                   const float* __restrict__ fc1w,
                                                   const float* __restrict__ fc2w,
                                                   const float* __restrict__ spw,
                                                   const float* __restrict__ qkvw,
                                                   const float* __restrict__ projw,
                                                   const float* __restrict__ projb) {
    __shared__ float tok[36][68];
    __shared__ float qb[36][68];
    __shared__ float kb[36][68];
    __shared__ float vb[36][68];
    __shared__ float att[144][37];
    __shared__ float pmean[64], pmax[64], chv[64], hmlp[32];
    __shared__ float spm[36], spx[36], spa[36];
    int n = blockIdx.x, tid = threadIdx.x;
    float* hb = h + (size_t)n * 2304;
    for (int i = tid; i < 2304; i += 256) tok[i % 36][i / 36] = hb[i];
    __syncthreads();
    if (tid < 64) {
        float m = 0.f, mx = -1e30f;
        for (int p = 0; p < 36; p++) { float v = tok[p][tid]; m += v; mx = fmaxf(mx, v); }
        pmean[tid] = m * (1.f / 36.f);
        pmax[tid] = mx;
    }
    __syncthreads();
    if (tid < 32) {
        int j = tid & 15;
        const float* src = (tid < 16) ? pmean : pmax;
        float s = 0.f;
        for (int c = 0; c < 64; c++) s += fc1w[j * 64 + c] * src[c];
        hmlp[tid] = fmaxf(s, 0.f);
    }
    __syncthreads();
    if (tid < 64) {
        float s = 0.f;
        for (int j = 0; j < 16; j++) s += fc2w[tid * 16 + j] * (hmlp[j] + hmlp[16 + j]);
        chv[tid] = 1.f / (1.f + expf(-s));
    }
    __syncthreads();
    if (tid < 36) {
        float m = 0.f, mx = -1e30f;
        for (int c = 0; c < 64; c++) {
            float v = tok[tid][c] * chv[c];
            tok[tid][c] = v;
            m += v; mx = fmaxf(mx, v);
        }
        spm[tid] = m * (1.f / 64.f);
        spx[tid] = mx;
    }
    __syncthreads();
    if (tid < 36) {
        int y = tid / 6, x = tid % 6;
        float s = 0.f;
        for (int dy = 0; dy < 7; dy++) {
            int yy = y + dy - 3;
            if (yy < 0 || yy > 5) continue;
            for (int dx = 0; dx < 7; dx++) {
                int xx = x + dx - 3;
                if (xx < 0 || xx > 5) continue;
                int pp = yy * 6 + xx;
                s += spw[dy * 7 + dx] * spm[pp] + spw[49 + dy * 7 + dx] * spx[pp];
            }
        }
        spa[tid] = 1.f / (1.f + expf(-s));
    }
    __syncthreads();
    if (tid < 36) {
        float sc = spa[tid];
        for (int c = 0; c < 64; c++) tok[tid][c] *= sc;
    }
    __syncthreads();
    // QKV projection
    for (int i = tid; i < 36 * 192; i += 256) {
        int p = i / 192, g = i % 192;
        const float4* wr4 = (const float4*)(qkvw + g * 64);
        const float4* t4 = (const float4*)(&tok[p][0]);
        float s = 0.f;
#pragma unroll
        for (int c4 = 0; c4 < 16; c4++) {
            float4 w = wr4[c4], tv = t4[c4];
            s += w.x * tv.x + w.y * tv.y + w.z * tv.z + w.w * tv.w;
        }
        int which = g >> 6, col = g & 63;
        if (which == 0) qb[p][col] = s;
        else if (which == 1) kb[p][col] = s;
        else vb[p][col] = s;
    }
    __syncthreads();
    // scores = q k^T * 0.25
    for (int i = tid; i < 5184; i += 256) {
        int hh = i / 1296, r = i % 1296, p = r / 36, p2 = r % 36;
        const float4* q4 = (const float4*)(&qb[p][hh * 16]);
        const float4* k4 = (const float4*)(&kb[p2][hh * 16]);
        float s = 0.f;
#pragma unroll
        for (int d = 0; d < 4; d++) {
            float4 a = q4[d], b = k4[d];
            s += a.x * b.x + a.y * b.y + a.z * b.z + a.w * b.w;
        }
        att[hh * 36 + p][p2] = s * 0.25f;
    }
    __syncthreads();
    if (tid < 144) {
        float mx = -1e30f;
        for (int j = 0; j < 36; j++) mx = fmaxf(mx, att[tid][j]);
        float sum = 0.f;
        for (int j = 0; j < 36; j++) { float e = expf(att[tid][j] - mx); att[tid][j] = e; sum += e; }
        float inv = 1.f / sum;
        for (int j = 0; j < 36; j++) att[tid][j] *= inv;
    }
    __syncthreads();
    // out = att @ v  -> store into kb (dead)
    for (int i = tid; i < 2304; i += 256) {
        int p = i / 64, c = i % 64, hh = c >> 4;
        const float* ar = &att[hh * 36 + p][0];
        float s = 0.f;
        for (int p2 = 0; p2 < 36; p2++) s += ar[p2] * vb[p2][c];
        qb[p][c] = s;  // qb dead after scores
    }
    __syncthreads();
    // proj + residual; write back CHW-coalesced
    for (int i = tid; i < 2304; i += 256) {
        int c = i / 36, p = i % 36;
        const float4* wr4 = (const float4*)(projw + c * 64);
        const float4* o4 = (const float4*)(&qb[p][0]);
        float s = projb[c];
#pragma unroll
        for (int j = 0; j < 16; j++) {
            float4 w = wr4[j], ov = o4[j];
            s += w.x * ov.x + w.y * ov.y + w.z * ov.z + w.w * ov.w;
        }
        hb[i] = tok[p][c] + s;
    }
}

// ---------------- generic tiled GEMM: C = act(A(MxK) @ Bw(NxK)^T + bias) ----
template <int ACT>
__global__ __launch_bounds__(256) void k_gemm(const float* __restrict__ A,
                                              const float* __restrict__ Bw,
                                              const float* __restrict__ bias,
                                              float* __restrict__ C,
                                              int M, int N, int K) {
    __shared__ float as[32][33];
    __shared__ float bs[32][33];
    int tx = threadIdx.x % 16, ty = threadIdx.x / 16;
    int bm = blockIdx.y * 32, bn = blockIdx.x * 32;
    float acc00 = 0.f, acc01 = 0.f, acc10 = 0.f, acc11 = 0.f;
    for (int k0 = 0; k0 < K; k0 += 32) {
        for (int i = threadIdx.x; i < 1024; i += 256) {
            int r = i / 32, c = i % 32;
            as[r][c] = A[(size_t)(bm + r) * K + k0 + c];
            bs[r][c] = Bw[(size_t)(bn + r) * K + k0 + c];
        }
        __syncthreads();
#pragma unroll 8
        for (int k = 0; k < 32; k++) {
            float a0 = as[ty * 2][k], a1 = as[ty * 2 + 1][k];
            float b0 = bs[tx * 2][k], b1 = bs[tx * 2 + 1][k];
            acc00 += a0 * b0; acc01 += a0 * b1;
            acc10 += a1 * b0; acc11 += a1 * b1;
        }
        __syncthreads();
    }
    int m0 = bm + ty * 2, n0 = bn + tx * 2;
    float r[2][2] = {{acc00, acc01}, {acc10, acc11}};
#pragma unroll
    for (int i = 0; i < 2; i++)
#pragma unroll
        for (int j = 0; j < 2; j++) {
            float v = r[i][j] + bias[n0 + j];
            if (ACT) v = fmaxf(v, 0.f);
            C[(size_t)(m0 + i) * N + n0 + j] = v;
        }
}

// ---------------- masked GRU scan: 16 co-resident blocks + grid barrier ----
__global__ __launch_bounds__(256) void k_gru(const float* __restrict__ GX,   // (64*32, 384)
                                             const float* __restrict__ done, // (2048,)
                                             const float* __restrict__ h0,   // (32,128)
                                             const float* __restrict__ whh,  // (384,128)
                                             const float* __restrict__ bhh,  // (384,)
                                             float* __restrict__ hs,         // (64,32,128)
                                             unsigned* __restrict__ bar) {
    int blk = blockIdx.x;
    int d0 = blk * 8;
    __shared__ float wl[24][128];
    __shared__ float hbuf[32][132];  // padded: 16B-aligned rows
    for (int i = threadIdx.x; i < 24 * 128; i += 256) {
        int r = i / 128, k = i % 128;
        int g = r / 8, dl = r % 8;
        wl[r][k] = whh[(size_t)(g * 128 + d0 + dl) * 128 + k];
    }
    int b = threadIdx.x & 31, dl = threadIdx.x >> 5;
    int d = d0 + dl;
    float bh_r = bhh[d], bh_z = bhh[128 + d], bh_n = bhh[256 + d];
    for (int t = 0; t < 64; t++) {
        __syncthreads();  // previous iter's hbuf reads done
        const float* hsrc = (t == 0) ? h0 : (hs + (size_t)(t - 1) * 4096);
        for (int i = threadIdx.x; i < 4096; i += 256) {
            int bb = i >> 7, k = i & 127;
            float dt = done[t * 32 + bb];
            hbuf[bb][k] = hsrc[i] * (1.f - dt);
        }
        __syncthreads();
        const float4* h4 = (const float4*)(&hbuf[b][0]);
        const float4* wr4 = (const float4*)(&wl[dl][0]);
        const float4* wz4 = (const float4*)(&wl[8 + dl][0]);
        const float4* wn4 = (const float4*)(&wl[16 + dl][0]);
        float sr = bh_r, sz = bh_z, sn = bh_n;
#pragma unroll 8
        for (int k = 0; k < 32; k++) {
            float4 hv = h4[k];
            float4 a = wr4[k], bz = wz4[k], cn = wn4[k];
            sr += a.x * hv.x + a.y * hv.y + a.z * hv.z + a.w * hv.w;
            sz += bz.x * hv.x + bz.y * hv.y + bz.z * hv.z + bz.w * hv.w;
            sn += cn.x * hv.x + cn.y * hv.y + cn.z * hv.z + cn.w * hv.w;
        }
        const float* gx = GX + (size_t)(t * 32 + b) * 384;
        float xr = gx[d], xz = gx[128 + d], xn = gx[256 + d];
        float hc = hbuf[b][d];
        float rg = 1.f / (1.f + expf(-(xr + sr)));
        float zg = 1.f / (1.f + expf(-(xz + sz)));
        float ng = tanhf(xn + rg * sn);
        float hnew = (1.f - zg) * ng + zg * hc;
        hs[(size_t)t * 4096 + b * 128 + d] = hnew;
        __threadfence();
        __syncthreads();
        if (threadIdx.x == 0) {
            atomicAdd(bar, 1u);
            unsigned target = 16u * (unsigned)(t + 1);
            while (atomicAdd(bar, 0u) < target) { __builtin_amdgcn_s_sleep(2); }
            __threadfence();
        }
        __syncthreads();
    }
}

// ---------------- critic head ----------------
__global__ __launch_bounds__(256) void k_critic(const float* __restrict__ hs,
                                                const float* __restrict__ crw,
                                                const float* __restrict__ crb,
                                                float* __restrict__ out) {
    int wave = threadIdx.x >> 6, lane = threadIdx.x & 63;
    int row = blockIdx.x * 4 + wave;
    const float* hr = hs + (size_t)row * 128;
    float s = hr[lane] * crw[lane] + hr[64 + lane] * crw[64 + lane];
#pragma unroll
    for (int off = 32; off; off >>= 1) s += __shfl_down(s, off);
    if (lane == 0) out[row] = s + crb[0];
}

extern "C" void kernel_launch(void* const* d_in, const int* in_sizes, int n_in,
                              void* d_out, int out_size, void* d_ws, size_t ws_size,
                              hipStream_t stream) {
    const float* x      = (const float*)d_in[0];
    const float* done   = (const float*)d_in[1];
    const float* gru0   = (const float*)d_in[2];
    const float* c1w    = (const float*)d_in[3];
    const float* c1b    = (const float*)d_in[4];
    const float* c2w    = (const float*)d_in[5];
    const float* c2b    = (const float*)d_in[6];
    const float* c3w    = (const float*)d_in[7];
    const float* c3b    = (const float*)d_in[8];
    const float* fc1w   = (const float*)d_in[9];
    const float* fc2w   = (const float*)d_in[10];
    const float* spw    = (const float*)d_in[11];
    const float* qkvw   = (const float*)d_in[12];
    const float* projw  = (const float*)d_in[13];
    const float* projb  = (const float*)d_in[14];
    const float* fcw    = (const float*)d_in[15];
    const float* fcb    = (const float*)d_in[16];
    const float* wih    = (const float*)d_in[17];
    const float* whh    = (const float*)d_in[18];
    const float* bih    = (const float*)d_in[19];
    const float* bhh    = (const float*)d_in[20];
    const float* crw    = (const float*)d_in[21];
    const float* crb    = (const float*)d_in[22];
    float* out = (float*)d_out;

    float* ws = (float*)d_ws;
    float* h2   = ws;                       // 2048*64*169 = 22,151,168
    float* h1c  = h2 + 22151168;            // 512*32*784  = 12,845,056
    float* h3   = h1c + 12845056;           // 2048*2304   =  4,718,592
    float* f256 = h3 + 4718592;             // 2048*256
    float* gxb  = f256 + 524288;            // 2048*384
    float* hsb  = gxb + 786432;             // 64*32*128
    float* wt1  = hsb + 262144;             // 8192
    float* wt2  = wt1 + 8192;               // 32768
    float* wt3  = wt2 + 32768;              // 36864
    unsigned* bar = (unsigned*)(wt3 + 36864);

    k_prep<<<144, 256, 0, stream>>>(c1w, c2w, c3w, wt1, wt2, wt3);
    hipMemsetAsync(bar, 0, sizeof(unsigned) * 4, stream);

    const int CHUNK = 512;
    for (int cc = 0; cc < 2048; cc += CHUNK) {
        k_conv1<<<(CHUNK * 392) / 256, 256, 0, stream>>>(x, wt1, c1b, h1c, cc, CHUNK);
        k_conv2<<<(CHUNK * 91) / 256, 256, 0, stream>>>(h1c, wt2, c2b, h2, cc, CHUNK);
    }
    k_conv3<<<(2048 * 36) / 256, 256, 0, stream>>>(h2, wt3, c3b, h3);
    k_cbam_attn<<<2048, 256, 0, stream>>>(h3, fc1w, fc2w, spw, qkvw, projw, projb);
    {
        dim3 g1(256 / 32, 2048 / 32);
        k_gemm<1><<<g1, 256, 0, stream>>>(h3, fcw, fcb, f256, 2048, 256, 2304);
        dim3 g2(384 / 32, 2048 / 32);
        k_gemm<0><<<g2, 256, 0, stream>>>(f256, wih, bih, gxb, 2048, 384, 256);
    }
    k_gru<<<16, 256, 0, stream>>>(gxb, done, gru0, whh, bhh, hsb, bar);
    k_critic<<<2048 / 4, 256, 0, stream>>>(hsb, crw, crb, out);
}

// Round 2
// 1760.094 us; speedup vs baseline: 1.7806x; 1.7806x over previous
//
#include <hip/hip_runtime.h>
#include <math.h>

typedef _Float16 f16;
typedef f16 f16x8 __attribute__((ext_vector_type(8)));
typedef f16 f16x2 __attribute__((ext_vector_type(2)));
typedef float f32x4 __attribute__((ext_vector_type(4)));

// ---------------- weight prep: fp32 -> fp16, conv weights to [n][k] with
// k-order matching the conv A-staging chunk layout ----------------
__global__ __launch_bounds__(256) void k_prep(const float* __restrict__ c1w,
                                              const float* __restrict__ c2w,
                                              const float* __restrict__ c3w,
                                              const float* __restrict__ fcw,
                                              const float* __restrict__ wih,
                                              f16* __restrict__ W1, f16* __restrict__ W2,
                                              f16* __restrict__ W3, f16* __restrict__ FCW,
                                              f16* __restrict__ WIH) {
    int i0 = blockIdx.x * 256 + threadIdx.x;
    if (i0 < 8192) {                       // conv1: k = kh*32 + c*8 + kw
        int n = i0 >> 8, k = i0 & 255;
        int kh = k >> 5, r = k & 31, c = r >> 3, kw = r & 7;
        W1[i0] = (f16)c1w[((n * 4 + c) * 8 + kh) * 8 + kw];
    } else if (i0 < 8192 + 32768) {        // conv2: k = kh*128 + kw*32 + c
        int i = i0 - 8192;
        int n = i >> 9, k = i & 511;
        int kh = k >> 7, r = k & 127, kw = r >> 5, c = r & 31;
        W2[i] = (f16)c2w[((n * 32 + c) * 4 + kh) * 4 + kw];
    } else if (i0 < 8192 + 32768 + 36864) {  // conv3: k = kh*192 + kw*64 + c
        int i = i0 - (8192 + 32768);
        int n = i / 576, k = i % 576;
        int kh = k / 192, r = k % 192, kw = r / 64, c = r & 63;
        W3[i] = (f16)c3w[((n * 64 + c) * 3 + kh) * 3 + kw];
    } else if (i0 < 8192 + 32768 + 36864 + 589824) {  // FC: k = p*64 + c (NHWC flat)
        int i = i0 - (8192 + 32768 + 36864);
        int o = i / 2304, k = i % 2304, p = k >> 6, c = k & 63;
        FCW[i] = (f16)fcw[o * 2304 + c * 36 + p];
    } else if (i0 < 765952) {
        int i = i0 - (8192 + 32768 + 36864 + 589824);
        WIH[i] = (f16)wih[i];
    }
}

// ---------------- implicit-GEMM MFMA conv (NHWC fp16 in/out, ReLU) --------
// Block = 64 output pixels (4 waves x 16-pixel m-tiles) x all NCH channels.
// K-loop chunks over kh; within-chunk k = contiguous (kw,c) run in NHWC.
template <int CINP, int KH, int KW, int STRIDE, int IW, int OW, int PPI, int NCH, bool SRCF32>
__global__ __launch_bounds__(256) void k_conv(const void* __restrict__ srcv,
                                              const f16* __restrict__ W,  // [NCH][KH*CK]
                                              const float* __restrict__ bias,
                                              f16* __restrict__ dst) {
    constexpr int CK = KW * CINP;      // within-chunk K (32 / 128 / 192)
    constexpr int KS = CK / 32;        // MFMA k-steps per chunk
    constexpr int NT = NCH / 16;       // n-tiles
    constexpr int LA = CK + 8;         // padded LDS row (halves): 16B-aligned, conflict-free
    constexpr int AUN = SRCF32 ? 64 * CINP : (64 * CK) / 8;
    constexpr int WUN = (NCH * CK) / 8;
    constexpr int ANU = (AUN + 255) / 256;
    constexpr int WNU = (WUN + 255) / 256;
    __shared__ f16 As[64 * LA];
    __shared__ f16 Bs[NCH * LA];
    const int tid = threadIdx.x;
    const int wave = tid >> 6, lane = tid & 63;
    const int m0 = blockIdx.x * 64;

    int aGB[ANU], aLO[ANU];
#pragma unroll
    for (int j = 0; j < ANU; j++) {
        int u = tid + j * 256;
        if (u < AUN) {
            if (SRCF32) {  // conv1: src NCHW fp32; unit = (pixel, channel-plane), 8-float run
                int px = u / CINP, c = u % CINP;
                int m = m0 + px, n = m / PPI, pp = m % PPI, oy = pp / OW, ox = pp % OW;
                aGB[j] = ((n * CINP + c) * IW + oy * STRIDE) * IW + ox * STRIDE;
                aLO[j] = px * LA + c * 8;
            } else {       // NHWC fp16: unit = 16B segment of the contiguous KW*CINP run
                constexpr int SPP = CK / 8;
                int px = u / SPP, seg = u % SPP;
                int m = m0 + px, n = m / PPI, pp = m % PPI, oy = pp / OW, ox = pp % OW;
                aGB[j] = ((n * IW + oy * STRIDE) * IW + ox * STRIDE) * CINP + seg * 8;
                aLO[j] = px * LA + seg * 8;
            }
        }
    }
    int wGB[WNU], wLO[WNU];
#pragma unroll
    for (int j = 0; j < WNU; j++) {
        int u = tid + j * 256;
        if (u < WUN) {
            constexpr int SPP = CK / 8;
            int n = u / SPP, seg = u % SPP;
            wGB[j] = n * (KH * CK) + seg * 8;
            wLO[j] = n * LA + seg * 8;
        }
    }

    f32x4 acc[NT] = {};
    const f16* ap = As + (wave * 16 + (lane & 15)) * LA + (lane >> 4) * 8;
    const f16* bp = Bs + (lane & 15) * LA + (lane >> 4) * 8;

    for (int kh = 0; kh < KH; kh++) {
        __syncthreads();
#pragma unroll
        for (int j = 0; j < ANU; j++) {
            int u = tid + j * 256;
            if (u < AUN) {
                if (SRCF32) {
                    const float* s = (const float*)srcv + aGB[j] + kh * IW;
                    float4 v0 = *(const float4*)s;
                    float4 v1 = *(const float4*)(s + 4);
                    f16x8 h;
                    h[0] = (f16)v0.x; h[1] = (f16)v0.y; h[2] = (f16)v0.z; h[3] = (f16)v0.w;
                    h[4] = (f16)v1.x; h[5] = (f16)v1.y; h[6] = (f16)v1.z; h[7] = (f16)v1.w;
                    *(f16x8*)(As + aLO[j]) = h;
                } else {
                    const f16* s = (const f16*)srcv + aGB[j] + kh * (IW * CINP);
                    *(f16x8*)(As + aLO[j]) = *(const f16x8*)s;
                }
            }
        }
#pragma unroll
        for (int j = 0; j < WNU; j++) {
            int u = tid + j * 256;
            if (u < WUN)
                *(f16x8*)(Bs + wLO[j]) = *(const f16x8*)(W + wGB[j] + kh * CK);
        }
        __syncthreads();
#pragma unroll
        for (int ks = 0; ks < KS; ks++) {
            f16x8 af = *(const f16x8*)(ap + ks * 32);
#pragma unroll
            for (int nt = 0; nt < NT; nt++) {
                f16x8 bf = *(const f16x8*)(bp + nt * 16 * LA + ks * 32);
                acc[nt] = __builtin_amdgcn_mfma_f32_16x16x32_f16(af, bf, acc[nt], 0, 0, 0);
            }
        }
    }
    __syncthreads();
    {   // bias+ReLU, restage through LDS for coalesced fp16 NHWC store
        int rrow = wave * 16 + ((lane >> 4) << 2);
        int col = lane & 15;
#pragma unroll
        for (int nt = 0; nt < NT; nt++) {
            float bb = bias[nt * 16 + col];
#pragma unroll
            for (int r = 0; r < 4; r++) {
                float v = acc[nt][r] + bb;
                As[(rrow + r) * NCH + nt * 16 + col] = (f16)fmaxf(v, 0.f);
            }
        }
    }
    __syncthreads();
    constexpr int OUN = 64 * NCH / 8;
    for (int u = tid; u < OUN; u += 256) {
        int px = u / (NCH / 8), seg = u % (NCH / 8);
        *(f16x8*)(dst + (size_t)(m0 + px) * NCH + seg * 8) = *(const f16x8*)(As + px * NCH + seg * 8);
    }
}

// ---------------- MFMA GEMM: C = act(A(MxK,f16) @ W(NxK,f16)^T + bias) ----
template <bool RELU, bool OUTF32>
__global__ __launch_bounds__(256) void k_gemm16(const f16* __restrict__ A,
                                                const f16* __restrict__ W,
                                                const float* __restrict__ bias,
                                                void* __restrict__ Cv, int N, int K) {
    __shared__ f16 As[64 * 72];
    __shared__ f16 Bs[64 * 72];
    int tid = threadIdx.x, wave = tid >> 6, lane = tid & 63;
    int n0 = blockIdx.x * 64, m0 = blockIdx.y * 64;
    f32x4 acc[4] = {};
    const f16* ap = As + (wave * 16 + (lane & 15)) * 72 + (lane >> 4) * 8;
    const f16* bp = Bs + (lane & 15) * 72 + (lane >> 4) * 8;
    int arow = tid >> 3, aseg = tid & 7;
    for (int k0 = 0; k0 < K; k0 += 64) {
        __syncthreads();
        *(f16x8*)(As + arow * 72 + aseg * 8) = *(const f16x8*)(A + (size_t)(m0 + arow) * K + k0 + aseg * 8);
        *(f16x8*)(As + (arow + 32) * 72 + aseg * 8) = *(const f16x8*)(A + (size_t)(m0 + arow + 32) * K + k0 + aseg * 8);
        *(f16x8*)(Bs + arow * 72 + aseg * 8) = *(const f16x8*)(W + (size_t)(n0 + arow) * K + k0 + aseg * 8);
        *(f16x8*)(Bs + (arow + 32) * 72 + aseg * 8) = *(const f16x8*)(W + (size_t)(n0 + arow + 32) * K + k0 + aseg * 8);
        __syncthreads();
#pragma unroll
        for (int ks = 0; ks < 2; ks++) {
            f16x8 af = *(const f16x8*)(ap + ks * 32);
#pragma unroll
            for (int nt = 0; nt < 4; nt++) {
                f16x8 bf = *(const f16x8*)(bp + nt * 16 * 72 + ks * 32);
                acc[nt] = __builtin_amdgcn_mfma_f32_16x16x32_f16(af, bf, acc[nt], 0, 0, 0);
            }
        }
    }
    int mrow = m0 + wave * 16 + ((lane >> 4) << 2);
    int col = n0 + (lane & 15);
#pragma unroll
    for (int nt = 0; nt < 4; nt++) {
        float bb = bias[col + nt * 16];
#pragma unroll
        for (int r = 0; r < 4; r++) {
            float v = acc[nt][r] + bb;
            if (RELU) v = fmaxf(v, 0.f);
            if (OUTF32) ((float*)Cv)[(size_t)(mrow + r) * N + col + nt * 16] = v;
            else ((f16*)Cv)[(size_t)(mrow + r) * N + col + nt * 16] = (f16)v;
        }
    }
}

// ---------------- CBAM + spatial self-attention (NHWC fp16 h3, fp32 math) --
__global__ __launch_bounds__(256) void k_cbam(f16* __restrict__ h3,
                                              const float* __restrict__ fc1w,
                                              const float* __restrict__ fc2w,
                                              const float* __restrict__ spw,
                                              const float* __restrict__ qkvw,
                                              const float* __restrict__ projw,
                                              const float* __restrict__ projb) {
    __shared__ float tok[36][68];
    __shared__ f16 qs[36][72], ksb[36][72], vs[36][72];
    __shared__ f16 att[144][40];
    __shared__ float pmean[64], pmax[64], chv[64], hmlp[32], spm[36], spx[36];
    int tid = threadIdx.x;
    f16* hb = h3 + (size_t)blockIdx.x * 2304;
    for (int i = tid; i < 2304; i += 256) tok[i >> 6][i & 63] = (float)hb[i];
    __syncthreads();
    if (tid < 64) {
        float m = 0.f, mx = -1e30f;
        for (int p = 0; p < 36; p++) { float v = tok[p][tid]; m += v; mx = fmaxf(mx, v); }
        pmean[tid] = m * (1.f / 36.f); pmax[tid] = mx;
    }
    __syncthreads();
    if (tid < 32) {
        int j = tid & 15;
        const float* src = (tid < 16) ? pmean : pmax;
        float s = 0.f;
        for (int c = 0; c < 64; c++) s += fc1w[j * 64 + c] * src[c];
        hmlp[tid] = fmaxf(s, 0.f);
    }
    __syncthreads();
    if (tid < 64) {
        float s = 0.f;
        for (int j = 0; j < 16; j++) s += fc2w[tid * 16 + j] * (hmlp[j] + hmlp[16 + j]);
        chv[tid] = 1.f / (1.f + expf(-s));
    }
    __syncthreads();
    if (tid < 36) {
        float m = 0.f, mx = -1e30f;
        for (int c = 0; c < 64; c++) {
            float v = tok[tid][c] * chv[c];
            tok[tid][c] = v; m += v; mx = fmaxf(mx, v);
        }
        spm[tid] = m * (1.f / 64.f); spx[tid] = mx;
    }
    __syncthreads();
    if (tid < 36) {
        int y = tid / 6, x = tid % 6;
        float s = 0.f;
        for (int dy = 0; dy < 7; dy++) {
            int yy = y + dy - 3; if (yy < 0 || yy > 5) continue;
            for (int dx = 0; dx < 7; dx++) {
                int xx = x + dx - 3; if (xx < 0 || xx > 5) continue;
                int pp = yy * 6 + xx;
                s += spw[dy * 7 + dx] * spm[pp] + spw[49 + dy * 7 + dx] * spx[pp];
            }
        }
        float g = 1.f / (1.f + expf(-s));
        for (int c = 0; c < 64; c++) tok[tid][c] *= g;
    }
    __syncthreads();
    // QKV (q pre-scaled by 1/sqrt(hd)=0.25)
    for (int i = tid; i < 6912; i += 256) {
        int p = i / 192, g = i % 192;
        const float4* wr = (const float4*)(qkvw + g * 64);
        const float4* t4 = (const float4*)(&tok[p][0]);
        float s = 0.f;
#pragma unroll
        for (int j = 0; j < 16; j++) {
            float4 w = wr[j], t = t4[j];
            s += w.x * t.x + w.y * t.y + w.z * t.z + w.w * t.w;
        }
        int which = g >> 6, col = g & 63;
        if (which == 0) qs[p][col] = (f16)(s * 0.25f);
        else if (which == 1) ksb[p][col] = (f16)s;
        else vs[p][col] = (f16)s;
    }
    __syncthreads();
    for (int i = tid; i < 5184; i += 256) {
        int h = i / 1296, r = i % 1296, p = r / 36, p2 = r % 36;
        f16x8 qa = *(const f16x8*)(&qs[p][h * 16]);
        f16x8 qb = *(const f16x8*)(&qs[p][h * 16 + 8]);
        f16x8 ka = *(const f16x8*)(&ksb[p2][h * 16]);
        f16x8 kb = *(const f16x8*)(&ksb[p2][h * 16 + 8]);
        float s = 0.f;
#pragma unroll
        for (int j = 0; j < 8; j++)
            s += (float)qa[j] * (float)ka[j] + (float)qb[j] * (float)kb[j];
        att[h * 36 + p][p2] = (f16)s;
    }
    __syncthreads();
    if (tid < 144) {
        float mx = -1e30f;
        for (int j = 0; j < 36; j++) mx = fmaxf(mx, (float)att[tid][j]);
        float sum = 0.f; float e[36];
        for (int j = 0; j < 36; j++) { float v = __expf((float)att[tid][j] - mx); e[j] = v; sum += v; }
        float inv = 1.f / sum;
        for (int j = 0; j < 36; j++) att[tid][j] = (f16)(e[j] * inv);
    }
    __syncthreads();
    // out = att @ v  -> overwrite qs (dead after scores)
    for (int i = tid; i < 1152; i += 256) {
        int p = i >> 5, cp = i & 31, c0 = cp * 2, h = c0 >> 4;
        const f16* ar = &att[h * 36 + p][0];
        float s0 = 0.f, s1 = 0.f;
        for (int p2 = 0; p2 < 36; p2++) {
            float a = (float)ar[p2];
            f16x2 vv = *(const f16x2*)(&vs[p2][c0]);
            s0 += a * (float)vv[0]; s1 += a * (float)vv[1];
        }
        f16x2 o; o[0] = (f16)s0; o[1] = (f16)s1;
        *(f16x2*)(&qs[p][c0]) = o;
    }
    __syncthreads();
    // proj + residual, coalesced NHWC write
    for (int i = tid; i < 2304; i += 256) {
        int p = i >> 6, c = i & 63;
        const float4* wr = (const float4*)(projw + c * 64);
        float s = projb[c];
#pragma unroll
        for (int j4 = 0; j4 < 8; j4++) {
            f16x8 ov = *(const f16x8*)(&qs[p][j4 * 8]);
            float4 w0 = wr[j4 * 2], w1 = wr[j4 * 2 + 1];
            s += w0.x * (float)ov[0] + w0.y * (float)ov[1] + w0.z * (float)ov[2] + w0.w * (float)ov[3]
               + w1.x * (float)ov[4] + w1.y * (float)ov[5] + w1.z * (float)ov[6] + w1.w * (float)ov[7];
        }
        hb[i] = (f16)(tok[p][c] + s);
    }
}

// ---------------- masked GRU scan: 16 co-resident blocks + grid barrier ----
__global__ __launch_bounds__(256) void k_gru(const float* __restrict__ GX,
                                             const float* __restrict__ done,
                                             const float* __restrict__ h0,
                                             const float* __restrict__ whh,
                                             const float* __restrict__ bhh,
                                             float* __restrict__ hs,
                                             unsigned* __restrict__ bar) {
    int blk = blockIdx.x;
    int d0 = blk * 8;
    __shared__ float wl[24][128];
    __shared__ float hbuf[32][132];
    for (int i = threadIdx.x; i < 24 * 128; i += 256) {
        int r = i / 128, k = i % 128;
        int g = r / 8, dl = r % 8;
        wl[r][k] = whh[(size_t)(g * 128 + d0 + dl) * 128 + k];
    }
    int b = threadIdx.x & 31, dl = threadIdx.x >> 5;
    int d = d0 + dl;
    float bh_r = bhh[d], bh_z = bhh[128 + d], bh_n = bhh[256 + d];
    for (int t = 0; t < 64; t++) {
        __syncthreads();
        const float* hsrc = (t == 0) ? h0 : (hs + (size_t)(t - 1) * 4096);
        for (int i = threadIdx.x; i < 4096; i += 256) {
            int bb = i >> 7, k = i & 127;
            float dt = done[t * 32 + bb];
            hbuf[bb][k] = hsrc[i] * (1.f - dt);
        }
        __syncthreads();
        const float4* h4 = (const float4*)(&hbuf[b][0]);
        const float4* wr4 = (const float4*)(&wl[dl][0]);
        const float4* wz4 = (const float4*)(&wl[8 + dl][0]);
        const float4* wn4 = (const float4*)(&wl[16 + dl][0]);
        float sr = bh_r, sz = bh_z, sn = bh_n;
#pragma unroll 8
        for (int k = 0; k < 32; k++) {
            float4 hv = h4[k];
            float4 a = wr4[k], bz = wz4[k], cn = wn4[k];
            sr += a.x * hv.x + a.y * hv.y + a.z * hv.z + a.w * hv.w;
            sz += bz.x * hv.x + bz.y * hv.y + bz.z * hv.z + bz.w * hv.w;
            sn += cn.x * hv.x + cn.y * hv.y + cn.z * hv.z + cn.w * hv.w;
        }
        const float* gx = GX + (size_t)(t * 32 + b) * 384;
        float xr = gx[d], xz = gx[128 + d], xn = gx[256 + d];
        float hc = hbuf[b][d];
        float rg = 1.f / (1.f + expf(-(xr + sr)));
        float zg = 1.f / (1.f + expf(-(xz + sz)));
        float ng = tanhf(xn + rg * sn);
        float hnew = (1.f - zg) * ng + zg * hc;
        hs[(size_t)t * 4096 + b * 128 + d] = hnew;
        __threadfence();
        __syncthreads();
        if (threadIdx.x == 0) {
            atomicAdd(bar, 1u);
            unsigned target = 16u * (unsigned)(t + 1);
            while (atomicAdd(bar, 0u) < target) { __builtin_amdgcn_s_sleep(2); }
            __threadfence();
        }
        __syncthreads();
    }
}

// ---------------- critic head ----------------
__global__ __launch_bounds__(256) void k_critic(const float* __restrict__ hs,
                                                const float* __restrict__ crw,
                                                const float* __restrict__ crb,
                                                float* __restrict__ out) {
    int wave = threadIdx.x >> 6, lane = threadIdx.x & 63;
    int row = blockIdx.x * 4 + wave;
    const float* hr = hs + (size_t)row * 128;
    float s = hr[lane] * crw[lane] + hr[64 + lane] * crw[64 + lane];
#pragma unroll
    for (int off = 32; off; off >>= 1) s += __shfl_down(s, off);
    if (lane == 0) out[row] = s + crb[0];
}

extern "C" void kernel_launch(void* const* d_in, const int* in_sizes, int n_in,
                              void* d_out, int out_size, void* d_ws, size_t ws_size,
                              hipStream_t stream) {
    const float* x     = (const float*)d_in[0];
    const float* done  = (const float*)d_in[1];
    const float* gru0  = (const float*)d_in[2];
    const float* c1w   = (const float*)d_in[3];
    const float* c1b   = (const float*)d_in[4];
    const float* c2w   = (const float*)d_in[5];
    const float* c2b   = (const float*)d_in[6];
    const float* c3w   = (const float*)d_in[7];
    const float* c3b   = (const float*)d_in[8];
    const float* fc1w  = (const float*)d_in[9];
    const float* fc2w  = (const float*)d_in[10];
    const float* spw   = (const float*)d_in[11];
    const float* qkvw  = (const float*)d_in[12];
    const float* projw = (const float*)d_in[13];
    const float* projb = (const float*)d_in[14];
    const float* fcw   = (const float*)d_in[15];
    const float* fcb   = (const float*)d_in[16];
    const float* wih   = (const float*)d_in[17];
    const float* whh   = (const float*)d_in[18];
    const float* bih   = (const float*)d_in[19];
    const float* bhh   = (const float*)d_in[20];
    const float* crw   = (const float*)d_in[21];
    const float* crb   = (const float*)d_in[22];
    float* out = (float*)d_out;

    f16* h1   = (f16*)d_ws;                 // 2048*784*32
    f16* h2   = h1 + 51380224ull;           // 2048*169*64
    f16* h3   = h2 + 22151168ull;           // 2048*36*64
    f16* f256 = h3 + 4718592ull;            // 2048*256
    f16* W1   = f256 + 524288ull;           // 8192
    f16* W2   = W1 + 8192;                  // 32768
    f16* W3   = W2 + 32768;                 // 36864
    f16* FCW  = W3 + 36864;                 // 589824
    f16* WIH  = FCW + 589824;               // 98304
    float* gxb = (float*)(WIH + 98304);     // 2048*384 fp32
    float* hsb = gxb + 786432;              // 64*32*128 fp32
    unsigned* bar = (unsigned*)(hsb + 262144);

    k_prep<<<2992, 256, 0, stream>>>(c1w, c2w, c3w, fcw, wih, W1, W2, W3, FCW, WIH);
    hipMemsetAsync(bar, 0, 16, stream);

    k_conv<4, 8, 8, 4, 116, 28, 784, 32, true><<<25088, 256, 0, stream>>>(x, W1, c1b, h1);
    k_conv<32, 4, 4, 2, 28, 13, 169, 64, false><<<5408, 256, 0, stream>>>(h1, W2, c2b, h2);
    k_conv<64, 3, 3, 2, 13, 6, 36, 64, false><<<1152, 256, 0, stream>>>(h2, W3, c3b, h3);
    k_cbam<<<2048, 256, 0, stream>>>(h3, fc1w, fc2w, spw, qkvw, projw, projb);
    k_gemm16<true, false><<<dim3(4, 32), 256, 0, stream>>>(h3, FCW, fcb, f256, 256, 2304);
    k_gemm16<false, true><<<dim3(6, 32), 256, 0, stream>>>(f256, WIH, bih, gxb, 384, 256);
    k_gru<<<16, 256, 0, stream>>>(gxb, done, gru0, whh, bhh, hsb, bar);
    k_critic<<<512, 256, 0, stream>>>(hsb, crw, crb, out);
}